// Round 8
// baseline (85317.334 us; speedup 1.0000x reference)
//
#include <hip/hip_runtime.h>
#include <hip/hip_bf16.h>
#include <stdint.h>

// CharLSTM persistent-RNN kernel for MI355X.
// Inputs f32; OUTPUT IS FLOAT32 (R7 telemetry proved it: bf16 sentinel at
// out[0] was invisible => harness reads f32 words; my packed-bf16 writes
// explained every absmax since R3 to 3 decimal places, incl. R1 NaN and
// R2 3.02 under the bias-x64 bug).
// 256 WGs (1/CU) x 512 threads. Wave v of WG w owns neuron j = 8w+v:
// all 4 gate rows (f,i,g,o) of that neuron live in per-thread registers
// (lane l holds h-cols [32l,32l+32) and x-cols [8l,8l+8) of each row).
// h is exchanged via tagged 64-bit agent-scope atomics: (f32<<32)|step;
// trajectory proven bit-identical to the pure grid.sync anchor (R5/R7).

#define T_STEPS 16384
#define HID     2048
#define EMBD    512
#define NCH     128
#define FANIN   (EMBD + HID)
#define NBLK    256
#define TPB     512
#define NEUR_PER_WG 8

static_assert(TPB == EMBD, "x staging assumes one thread per emb element");

__device__ __forceinline__ float sigmoid_f(float x) {
  return 1.0f / (1.0f + __expf(-x));
}
__device__ __forceinline__ float tanh_f(float x) {
  // tanh(x) = 1 - 2/(e^{2x}+1); saturates cleanly at +-1
  return 1.0f - 2.0f / (__expf(2.0f * x) + 1.0f);
}
__device__ __forceinline__ unsigned long long ld_agent(const unsigned long long* p) {
  return __hip_atomic_load(p, __ATOMIC_RELAXED, __HIP_MEMORY_SCOPE_AGENT);
}
__device__ __forceinline__ void st_agent(unsigned long long* p, unsigned long long v) {
  __hip_atomic_store(p, v, __ATOMIC_RELAXED, __HIP_MEMORY_SCOPE_AGENT);
}

__global__ __launch_bounds__(TPB) void lstm_persist(
    const int* __restrict__ seq,
    const float* __restrict__ emb,
    const float* __restrict__ Wf, const float* __restrict__ bfv,
    const float* __restrict__ Wi, const float* __restrict__ biv,
    const float* __restrict__ Wg, const float* __restrict__ bgv,
    const float* __restrict__ Wo, const float* __restrict__ bov,
    const float* __restrict__ Wfc, const float* __restrict__ bfc,
    unsigned long long* __restrict__ hbuf,   // [2][HID] tagged h
    float* __restrict__ out)                 // f32: [T][NCH] logits, h[HID], c[HID]
{
  __shared__ float h_lds[2][HID];
  __shared__ float x_lds[2][EMBD];

  const int tid  = threadIdx.x;
  const int wv   = tid >> 6;
  const int lane = tid & 63;
  const int j    = blockIdx.x * NEUR_PER_WG + wv;   // neuron this wave owns

  // seq dtype guard (selects int32 on this data; kept for safety)
  int shift = 1;
  for (int k = 0; k < 64; ++k) {
    if (seq[2 * k + 1] != 0) { shift = 0; break; }
  }

  // ---- preload recurrent + input weights into registers (f32) ----
  const float* Wmat[4] = {Wf, Wi, Wg, Wo};
  const float* bvec[4] = {bfv, biv, bgv, bov};
  float wh[4][32], wx[4][8], bias[4];
  #pragma unroll
  for (int g = 0; g < 4; ++g) {
    const float* rp = Wmat[g] + (size_t)j * FANIN;
    #pragma unroll
    for (int k = 0; k < 32; ++k) wh[g][k] = rp[EMBD + lane * 32 + k];
    #pragma unroll
    for (int k = 0; k < 8; ++k)  wx[g][k] = rp[lane * 8 + k];
    bias[g] = bvec[g][j];
  }

  // ---- logits duty: even WGs' wave 0 each own one output column ----
  int lcol = -1;
  float wfc_c[32];
  float bfc_c = 0.0f;
  if (((blockIdx.x & 1) == 0) && wv == 0) {
    lcol = blockIdx.x >> 1;                 // 0..127
    const float* wp = Wfc + (size_t)lcol * HID + lane * 32;
    #pragma unroll
    for (int u = 0; u < 32; ++u) wfc_c[u] = wp[u];
    bfc_c = bfc[lcol];
  }

  float creg = 0.0f;  // cell state (lane 0 only)
  const int i0 = tid, i1 = tid + TPB, i2 = tid + 2 * TPB, i3 = tid + 3 * TPB;

  for (int t = 0; t < T_STEPS; ++t) {
    const int bsel = t & 1;
    const unsigned long long* src = hbuf + (size_t)bsel * HID;
    const unsigned ut = (unsigned)t;

    // issue all 4 tagged-h loads up front, stage x while they fly
    unsigned long long v0 = ld_agent(src + i0), v1 = ld_agent(src + i1),
                       v2 = ld_agent(src + i2), v3 = ld_agent(src + i3);
    const int s = seq[(size_t)t << shift];
    x_lds[bsel][tid] = emb[(size_t)s * EMBD + tid];
    while ((unsigned)v0 != ut) v0 = ld_agent(src + i0);
    while ((unsigned)v1 != ut) v1 = ld_agent(src + i1);
    while ((unsigned)v2 != ut) v2 = ld_agent(src + i2);
    while ((unsigned)v3 != ut) v3 = ld_agent(src + i3);
    h_lds[bsel][i0] = __uint_as_float((unsigned)(v0 >> 32));
    h_lds[bsel][i1] = __uint_as_float((unsigned)(v1 >> 32));
    h_lds[bsel][i2] = __uint_as_float((unsigned)(v2 >> 32));
    h_lds[bsel][i3] = __uint_as_float((unsigned)(v3 >> 32));
    __syncthreads();

    // ---- 4 gate dot-products from register weights ----
    float a0 = 0.0f, a1 = 0.0f, a2 = 0.0f, a3 = 0.0f;
    const float* xp = &x_lds[bsel][lane * 8];
    #pragma unroll
    for (int k = 0; k < 8; ++k) {
      const float xv = xp[k];
      a0 = fmaf(wx[0][k], xv, a0); a1 = fmaf(wx[1][k], xv, a1);
      a2 = fmaf(wx[2][k], xv, a2); a3 = fmaf(wx[3][k], xv, a3);
    }
    const float* hp = &h_lds[bsel][lane * 32];
    #pragma unroll
    for (int k = 0; k < 32; ++k) {
      const float hv = hp[k];
      a0 = fmaf(wh[0][k], hv, a0); a1 = fmaf(wh[1][k], hv, a1);
      a2 = fmaf(wh[2][k], hv, a2); a3 = fmaf(wh[3][k], hv, a3);
    }
    #pragma unroll
    for (int off = 32; off > 0; off >>= 1) {
      a0 += __shfl_down(a0, off, 64);
      a1 += __shfl_down(a1, off, 64);
      a2 += __shfl_down(a2, off, 64);
      a3 += __shfl_down(a3, off, 64);
    }
    if (lane == 0) {
      const float fg = sigmoid_f(a0 + bias[0]);
      const float ig = sigmoid_f(a1 + bias[1]);
      const float gg = tanh_f(a2 + bias[2]);
      const float og = sigmoid_f(a3 + bias[3]);
      creg = fg * creg + ig * gg;
      const float hn = og * tanh_f(creg);
      const unsigned long long pk =
          ((unsigned long long)__float_as_uint(hn) << 32) | (unsigned long long)(unsigned)(t + 1);
      st_agent(&hbuf[(size_t)((t + 1) & 1) * HID + j], pk);   // publish ASAP
      if (t == T_STEPS - 1) {
        out[(size_t)T_STEPS * NCH + j]       = hn;     // final h (f32)
        out[(size_t)T_STEPS * NCH + HID + j] = creg;   // final c (f32)
      }
    }

    // ---- logits for step t-1 from already-staged h[t] (hidden latency) ----
    if (lcol >= 0 && t > 0) {
      const float* hq = &h_lds[bsel][lane * 32];
      float sacc = 0.0f;
      #pragma unroll
      for (int u = 0; u < 32; ++u) sacc = fmaf(wfc_c[u], hq[u], sacc);
      #pragma unroll
      for (int off = 32; off > 0; off >>= 1) sacc += __shfl_down(sacc, off, 64);
      if (lane == 0) out[(size_t)(t - 1) * NCH + lcol] = sacc + bfc_c;
    }
  }

  // ---- epilogue: stage h[T] (tag T, slot 0) and emit logits for t = T-1 ----
  {
    const unsigned long long* src = hbuf;  // T_STEPS & 1 == 0
    const unsigned ut = (unsigned)T_STEPS;
    unsigned long long v0 = ld_agent(src + i0), v1 = ld_agent(src + i1),
                       v2 = ld_agent(src + i2), v3 = ld_agent(src + i3);
    while ((unsigned)v0 != ut) v0 = ld_agent(src + i0);
    while ((unsigned)v1 != ut) v1 = ld_agent(src + i1);
    while ((unsigned)v2 != ut) v2 = ld_agent(src + i2);
    while ((unsigned)v3 != ut) v3 = ld_agent(src + i3);
    h_lds[0][i0] = __uint_as_float((unsigned)(v0 >> 32));
    h_lds[0][i1] = __uint_as_float((unsigned)(v1 >> 32));
    h_lds[0][i2] = __uint_as_float((unsigned)(v2 >> 32));
    h_lds[0][i3] = __uint_as_float((unsigned)(v3 >> 32));
    __syncthreads();
    if (lcol >= 0) {
      const float* hq = &h_lds[0][lane * 32];
      float sacc = 0.0f;
      #pragma unroll
      for (int u = 0; u < 32; ++u) sacc = fmaf(wfc_c[u], hq[u], sacc);
      #pragma unroll
      for (int off = 32; off > 0; off >>= 1) sacc += __shfl_down(sacc, off, 64);
      if (lane == 0) out[(size_t)(T_STEPS - 1) * NCH + lcol] = sacc + bfc_c;
    }
  }
}

extern "C" void kernel_launch(void* const* d_in, const int* in_sizes, int n_in,
                              void* d_out, int out_size, void* d_ws, size_t ws_size,
                              hipStream_t stream) {
  (void)in_sizes; (void)n_in; (void)out_size; (void)ws_size;
  const int* seq     = (const int*)d_in[0];
  const float* emb   = (const float*)d_in[1];
  const float* Wf    = (const float*)d_in[2];
  const float* bfv   = (const float*)d_in[3];
  const float* Wi    = (const float*)d_in[4];
  const float* biv   = (const float*)d_in[5];
  const float* Wg    = (const float*)d_in[6];
  const float* bgv   = (const float*)d_in[7];
  const float* Wo    = (const float*)d_in[8];
  const float* bov   = (const float*)d_in[9];
  const float* Wfc   = (const float*)d_in[10];
  const float* bfc   = (const float*)d_in[11];
  float* out         = (float*)d_out;
  unsigned long long* hbuf = (unsigned long long*)d_ws;   // 2*HID*8 = 32 KB

  // slot0 = h[0] = 0 with tag 0; slot1 zeroed (tag 0 never matches an odd step)
  hipMemsetAsync(d_ws, 0, 2 * HID * sizeof(unsigned long long), stream);

  void* args[] = {
    (void*)&seq, (void*)&emb,
    (void*)&Wf, (void*)&bfv, (void*)&Wi, (void*)&biv,
    (void*)&Wg, (void*)&bgv, (void*)&Wo, (void*)&bov,
    (void*)&Wfc, (void*)&bfc,
    (void*)&hbuf, (void*)&out
  };
  hipLaunchCooperativeKernel((const void*)lstm_persist, dim3(NBLK), dim3(TPB),
                             args, 0, stream);
}

// Round 9
// 82898.962 us; speedup vs baseline: 1.0292x; 1.0292x over previous
//
#include <hip/hip_runtime.h>
#include <hip/hip_bf16.h>
#include <stdint.h>

// CharLSTM persistent-RNN kernel for MI355X. f32 in / f32 out (proven R7/R8).
// 256 WGs (1/CU) x 512 threads. Wave v of WG w owns neuron j = 8w+v.
// R9: conflict-free stride-64 fragment layout — lane l owns h-cols {k*64+l},
//     x-cols {k*64+l}; kills the 8.3e9 SQ_LDS_BANK_CONFLICT of R8 (lane-major
//     stride-32 layout put all 64 lanes in one bank per read). Also makes the
//     weight preload perfectly coalesced. Poll retries now re-issue all
//     missing words per round (parallel) instead of chaining 4 serial loops.
// h exchanged via tagged 64-bit agent-scope atomics: (f32<<32)|(step tag).

#define T_STEPS 16384
#define HID     2048
#define EMBD    512
#define NCH     128
#define FANIN   (EMBD + HID)
#define NBLK    256
#define TPB     512
#define NEUR_PER_WG 8

static_assert(TPB == EMBD, "x staging assumes one thread per emb element");

__device__ __forceinline__ float sigmoid_f(float x) {
  return 1.0f / (1.0f + __expf(-x));
}
__device__ __forceinline__ float tanh_f(float x) {
  return 1.0f - 2.0f / (__expf(2.0f * x) + 1.0f);
}
__device__ __forceinline__ unsigned long long ld_agent(const unsigned long long* p) {
  return __hip_atomic_load(p, __ATOMIC_RELAXED, __HIP_MEMORY_SCOPE_AGENT);
}
__device__ __forceinline__ void st_agent(unsigned long long* p, unsigned long long v) {
  __hip_atomic_store(p, v, __ATOMIC_RELAXED, __HIP_MEMORY_SCOPE_AGENT);
}

__global__ __launch_bounds__(TPB) void lstm_persist(
    const int* __restrict__ seq,
    const float* __restrict__ emb,
    const float* __restrict__ Wf, const float* __restrict__ bfv,
    const float* __restrict__ Wi, const float* __restrict__ biv,
    const float* __restrict__ Wg, const float* __restrict__ bgv,
    const float* __restrict__ Wo, const float* __restrict__ bov,
    const float* __restrict__ Wfc, const float* __restrict__ bfc,
    unsigned long long* __restrict__ hbuf,   // [2][HID] tagged h
    float* __restrict__ out)                 // f32: [T][NCH] logits, h[HID], c[HID]
{
  __shared__ float h_lds[2][HID];
  __shared__ float x_lds[2][EMBD];

  const int tid  = threadIdx.x;
  const int wv   = tid >> 6;
  const int lane = tid & 63;
  const int j    = blockIdx.x * NEUR_PER_WG + wv;   // neuron this wave owns

  // seq dtype guard (selects int32 on this data; kept for safety)
  int shift = 1;
  for (int k = 0; k < 64; ++k) {
    if (seq[2 * k + 1] != 0) { shift = 0; break; }
  }

  // ---- preload weights, stride-64 layout: lane l owns cols {k*64+l} ----
  // (coalesced global reads; conflict-free LDS reads in the gate loop)
  const float* Wmat[4] = {Wf, Wi, Wg, Wo};
  const float* bvec[4] = {bfv, biv, bgv, bov};
  float wh[4][32], wx[4][8], bias[4];
  #pragma unroll
  for (int g = 0; g < 4; ++g) {
    const float* rp = Wmat[g] + (size_t)j * FANIN;
    #pragma unroll
    for (int k = 0; k < 32; ++k) wh[g][k] = rp[EMBD + k * 64 + lane];
    #pragma unroll
    for (int k = 0; k < 8; ++k)  wx[g][k] = rp[k * 64 + lane];
    bias[g] = bvec[g][j];
  }

  // ---- logits duty: even WGs' wave 0 each own one output column ----
  int lcol = -1;
  float wfc_c[32];
  float bfc_c = 0.0f;
  if (((blockIdx.x & 1) == 0) && wv == 0) {
    lcol = blockIdx.x >> 1;                 // 0..127
    const float* wp = Wfc + (size_t)lcol * HID;
    #pragma unroll
    for (int u = 0; u < 32; ++u) wfc_c[u] = wp[u * 64 + lane];
    bfc_c = bfc[lcol];
  }

  float creg = 0.0f;  // cell state (lane 0 only)
  const int i0 = tid, i1 = tid + TPB, i2 = tid + 2 * TPB, i3 = tid + 3 * TPB;

  for (int t = 0; t < T_STEPS; ++t) {
    const int bsel = t & 1;
    const unsigned long long* src = hbuf + (size_t)bsel * HID;
    const unsigned ut = (unsigned)t;

    // issue all 4 tagged-h loads up front, stage x while they fly
    unsigned long long v0 = ld_agent(src + i0), v1 = ld_agent(src + i1),
                       v2 = ld_agent(src + i2), v3 = ld_agent(src + i3);
    const int s = seq[(size_t)t << shift];
    x_lds[bsel][tid] = emb[(size_t)s * EMBD + tid];
    // parallel retry: re-issue all missing words each round (no serial chains)
    while (((unsigned)v0 != ut) | ((unsigned)v1 != ut) |
           ((unsigned)v2 != ut) | ((unsigned)v3 != ut)) {
      if ((unsigned)v0 != ut) v0 = ld_agent(src + i0);
      if ((unsigned)v1 != ut) v1 = ld_agent(src + i1);
      if ((unsigned)v2 != ut) v2 = ld_agent(src + i2);
      if ((unsigned)v3 != ut) v3 = ld_agent(src + i3);
    }
    h_lds[bsel][i0] = __uint_as_float((unsigned)(v0 >> 32));
    h_lds[bsel][i1] = __uint_as_float((unsigned)(v1 >> 32));
    h_lds[bsel][i2] = __uint_as_float((unsigned)(v2 >> 32));
    h_lds[bsel][i3] = __uint_as_float((unsigned)(v3 >> 32));
    __syncthreads();

    // ---- 4 gate dot-products; stride-64 reads are bank-conflict-free ----
    float a0 = 0.0f, a1 = 0.0f, a2 = 0.0f, a3 = 0.0f;
    const float* xp = &x_lds[bsel][lane];
    #pragma unroll
    for (int k = 0; k < 8; ++k) {
      const float xv = xp[k * 64];
      a0 = fmaf(wx[0][k], xv, a0); a1 = fmaf(wx[1][k], xv, a1);
      a2 = fmaf(wx[2][k], xv, a2); a3 = fmaf(wx[3][k], xv, a3);
    }
    const float* hp = &h_lds[bsel][lane];
    #pragma unroll
    for (int k = 0; k < 32; ++k) {
      const float hv = hp[k * 64];
      a0 = fmaf(wh[0][k], hv, a0); a1 = fmaf(wh[1][k], hv, a1);
      a2 = fmaf(wh[2][k], hv, a2); a3 = fmaf(wh[3][k], hv, a3);
    }
    #pragma unroll
    for (int off = 32; off > 0; off >>= 1) {
      a0 += __shfl_down(a0, off, 64);
      a1 += __shfl_down(a1, off, 64);
      a2 += __shfl_down(a2, off, 64);
      a3 += __shfl_down(a3, off, 64);
    }
    if (lane == 0) {
      const float fg = sigmoid_f(a0 + bias[0]);
      const float ig = sigmoid_f(a1 + bias[1]);
      const float gg = tanh_f(a2 + bias[2]);
      const float og = sigmoid_f(a3 + bias[3]);
      creg = fg * creg + ig * gg;
      const float hn = og * tanh_f(creg);
      const unsigned long long pk =
          ((unsigned long long)__float_as_uint(hn) << 32) | (unsigned long long)(unsigned)(t + 1);
      st_agent(&hbuf[(size_t)((t + 1) & 1) * HID + j], pk);   // publish ASAP
      if (t == T_STEPS - 1) {
        out[(size_t)T_STEPS * NCH + j]       = hn;     // final h
        out[(size_t)T_STEPS * NCH + HID + j] = creg;   // final c
      }
    }

    // ---- logits for step t-1 from already-staged h[t] (off critical path) ----
    if (lcol >= 0 && t > 0) {
      const float* hq = &h_lds[bsel][lane];
      float sacc = 0.0f;
      #pragma unroll
      for (int u = 0; u < 32; ++u) sacc = fmaf(wfc_c[u], hq[u * 64], sacc);
      #pragma unroll
      for (int off = 32; off > 0; off >>= 1) sacc += __shfl_down(sacc, off, 64);
      if (lane == 0) out[(size_t)(t - 1) * NCH + lcol] = sacc + bfc_c;
    }
  }

  // ---- epilogue: stage h[T] (tag T, slot 0) and emit logits for t = T-1 ----
  {
    const unsigned long long* src = hbuf;  // T_STEPS & 1 == 0
    const unsigned ut = (unsigned)T_STEPS;
    unsigned long long v0 = ld_agent(src + i0), v1 = ld_agent(src + i1),
                       v2 = ld_agent(src + i2), v3 = ld_agent(src + i3);
    while (((unsigned)v0 != ut) | ((unsigned)v1 != ut) |
           ((unsigned)v2 != ut) | ((unsigned)v3 != ut)) {
      if ((unsigned)v0 != ut) v0 = ld_agent(src + i0);
      if ((unsigned)v1 != ut) v1 = ld_agent(src + i1);
      if ((unsigned)v2 != ut) v2 = ld_agent(src + i2);
      if ((unsigned)v3 != ut) v3 = ld_agent(src + i3);
    }
    h_lds[0][i0] = __uint_as_float((unsigned)(v0 >> 32));
    h_lds[0][i1] = __uint_as_float((unsigned)(v1 >> 32));
    h_lds[0][i2] = __uint_as_float((unsigned)(v2 >> 32));
    h_lds[0][i3] = __uint_as_float((unsigned)(v3 >> 32));
    __syncthreads();
    if (lcol >= 0) {
      const float* hq = &h_lds[0][lane];
      float sacc = 0.0f;
      #pragma unroll
      for (int u = 0; u < 32; ++u) sacc = fmaf(wfc_c[u], hq[u * 64], sacc);
      #pragma unroll
      for (int off = 32; off > 0; off >>= 1) sacc += __shfl_down(sacc, off, 64);
      if (lane == 0) out[(size_t)(T_STEPS - 1) * NCH + lcol] = sacc + bfc_c;
    }
  }
}

extern "C" void kernel_launch(void* const* d_in, const int* in_sizes, int n_in,
                              void* d_out, int out_size, void* d_ws, size_t ws_size,
                              hipStream_t stream) {
  (void)in_sizes; (void)n_in; (void)out_size; (void)ws_size;
  const int* seq     = (const int*)d_in[0];
  const float* emb   = (const float*)d_in[1];
  const float* Wf    = (const float*)d_in[2];
  const float* bfv   = (const float*)d_in[3];
  const float* Wi    = (const float*)d_in[4];
  const float* biv   = (const float*)d_in[5];
  const float* Wg    = (const float*)d_in[6];
  const float* bgv   = (const float*)d_in[7];
  const float* Wo    = (const float*)d_in[8];
  const float* bov   = (const float*)d_in[9];
  const float* Wfc   = (const float*)d_in[10];
  const float* bfc   = (const float*)d_in[11];
  float* out         = (float*)d_out;
  unsigned long long* hbuf = (unsigned long long*)d_ws;   // 2*HID*8 = 32 KB

  hipMemsetAsync(d_ws, 0, 2 * HID * sizeof(unsigned long long), stream);

  void* args[] = {
    (void*)&seq, (void*)&emb,
    (void*)&Wf, (void*)&bfv, (void*)&Wi, (void*)&biv,
    (void*)&Wg, (void*)&bgv, (void*)&Wo, (void*)&bov,
    (void*)&Wfc, (void*)&bfc,
    (void*)&hbuf, (void*)&out
  };
  hipLaunchCooperativeKernel((const void*)lstm_persist, dim3(NBLK), dim3(TPB),
                             args, 0, stream);
}